// Round 4
// baseline (1201.039 us; speedup 1.0000x reference)
//
#include <hip/hip_runtime.h>
#include <hip/hip_bf16.h>
#include <stdint.h>

#define NN 512
#define HD 128
#define TJ 32

static __device__ __forceinline__ float bf2f(unsigned short u) {
  union { uint32_t u32; float f; } cv; cv.u32 = ((uint32_t)u) << 16; return cv.f;
}
static __device__ __forceinline__ unsigned short f2bf(float f) {
  union { float f; uint32_t u; } cv; cv.f = f;
  return (unsigned short)((cv.u + 0x7FFFu + ((cv.u >> 16) & 1u)) >> 16);
}

struct DetectArgs { const uint16_t* p[10]; int n[10]; };

// Per-tensor dtype sniffing (flags[ti]=1 -> fp32, 0 -> bf16). A bf16 buffer of
// moderate-scale data has ~100% of nonzero u16 words with exponent field in
// [90,133]; an fp32 buffer read as u16 passes only ~58% (mantissa-low words
// are uniform). Threshold 90%.
__global__ __launch_bounds__(64) void detect_kernel(DetectArgs a, int* __restrict__ flags) {
  __shared__ int acc[64];
  for (int ti = 0; ti < 10; ++ti) {
    int n = a.n[ti]; if (n > 2048) n = 2048;
    int g = 0;
    for (int w = threadIdx.x; w < n; w += 64) {
      uint16_t v = a.p[ti][w];
      int e = (v >> 7) & 0xFF;
      g += (v == 0u || (e >= 90 && e <= 133)) ? 1 : 0;
    }
    acc[threadIdx.x] = g;
    __syncthreads();
    if (threadIdx.x == 0) {
      int t = 0;
      #pragma unroll
      for (int k = 0; k < 64; ++k) t += acc[k];
      flags[ti] = (t * 10 < n * 9) ? 1 : 0;
    }
    __syncthreads();
  }
}

// Mask may arrive as int32{0,1}, float32{0,1.0f}, bf16, or byte-bool.
// Emit additive bias: 0.0f (keep) or -1e30f (masked; finite).
__global__ __launch_bounds__(256) void mask_bias_kernel(const uint32_t* __restrict__ raw,
                                                        float* __restrict__ mbias, int count) {
  int inspect = count >> 2; if (inspect > 256) inspect = 256;
  bool ok_i32 = true, ok_f32 = true, ok_bf16 = true;
  #pragma unroll 1
  for (int w = 0; w < inspect; ++w) {
    uint32_t v = raw[w];
    if (v > 1u) ok_i32 = false;
    if (!(v == 0u || v == 0x3F800000u)) ok_f32 = false;
    uint32_t lo = v & 0xFFFFu, hi = v >> 16;
    if (!((lo == 0u || lo == 0x3F80u) && (hi == 0u || hi == 0x3F80u))) ok_bf16 = false;
  }
  int idx = blockIdx.x * 256 + threadIdx.x;
  if (idx < count) {
    bool on;
    if (ok_i32 || ok_f32) on = raw[idx] != 0u;
    else if (ok_bf16)     on = ((const uint16_t*)raw)[idx] != 0u;
    else                  on = ((const uint8_t*)raw)[idx] != 0u;
    mbias[idx] = on ? 0.0f : -1e30f;
  }
}

// qkv = x @ Wqkv + bqkv ; q,k,v stored bf16 in workspace.
__global__ __launch_bounds__(128) void qkv_kernel(const void* __restrict__ xp,
                                                  const void* __restrict__ Wp,
                                                  const void* __restrict__ bp,
                                                  const int* __restrict__ flags,
                                                  uint16_t* __restrict__ qf,
                                                  uint16_t* __restrict__ kf,
                                                  uint16_t* __restrict__ vf) {
  const int f_x = flags[0], f_W = flags[2], f_b = flags[3];
  const int row = blockIdx.x;
  const int t = threadIdx.x;
  __shared__ float xs[HD];
  xs[t] = f_x ? ((const float*)xp)[row * HD + t] : bf2f(((const uint16_t*)xp)[row * HD + t]);
  __syncthreads();
  float aq = 0.f, ak = 0.f, av = 0.f;
  if (f_W) {
    const float* W = (const float*)Wp;
    #pragma unroll 4
    for (int kk = 0; kk < HD; ++kk) {
      float xv = xs[kk]; const float* wr = W + kk * 384;
      aq = fmaf(xv, wr[t], aq);
      ak = fmaf(xv, wr[128 + t], ak);
      av = fmaf(xv, wr[256 + t], av);
    }
  } else {
    const uint16_t* W = (const uint16_t*)Wp;
    #pragma unroll 4
    for (int kk = 0; kk < HD; ++kk) {
      float xv = xs[kk]; const uint16_t* wr = W + kk * 384;
      aq = fmaf(xv, bf2f(wr[t]), aq);
      ak = fmaf(xv, bf2f(wr[128 + t]), ak);
      av = fmaf(xv, bf2f(wr[256 + t]), av);
    }
  }
  float bq = f_b ? ((const float*)bp)[t]       : bf2f(((const uint16_t*)bp)[t]);
  float bk = f_b ? ((const float*)bp)[128 + t] : bf2f(((const uint16_t*)bp)[128 + t]);
  float bv = f_b ? ((const float*)bp)[256 + t] : bf2f(((const uint16_t*)bp)[256 + t]);
  qf[row * HD + t] = f2bf(aq + bq);
  kf[row * HD + t] = f2bf(ak + bk);
  vf[row * HD + t] = f2bf(av + bv);
}

// One block per (b, i). Fused pipeline. FP32 outputs.
__global__ __launch_bounds__(256) void gat_main_kernel(
    const void* __restrict__ eap,
    const void* __restrict__ Wep,  const void* __restrict__ bep,
    const void* __restrict__ Wnop, const void* __restrict__ bnop,
    const void* __restrict__ Weop, const void* __restrict__ beop,
    const int* __restrict__ flags,
    const uint16_t* __restrict__ qf, const uint16_t* __restrict__ kf,
    const uint16_t* __restrict__ vf, const float* __restrict__ mbias,
    float* __restrict__ node_out, float* __restrict__ edge_out) {
  const int tid = threadIdx.x;
  const int bb = blockIdx.x >> 9;
  const int i  = blockIdx.x & (NN - 1);
  const int f_ea = flags[1], f_We = flags[4], f_be = flags[5];
  const int f_Wno = flags[6], f_bno = flags[7], f_Weo = flags[8], f_beo = flags[9];

  __shared__ __align__(16) uint16_t We_s[64 * HD];    // 16 KB
  __shared__ __align__(16) uint16_t Weo_s[HD * 64];   // 16 KB
  __shared__ __align__(16) uint16_t ea_s[TJ * 64];    // 4 KB
  __shared__ __align__(16) float raw_s[TJ * HD];      // 16 KB
  __shared__ __align__(16) uint16_t att_s[NN * 8];    // 8 KB
  __shared__ __align__(16) float q_s[HD];
  __shared__ __align__(16) float be_s[HD];
  __shared__ __align__(16) float beo_s[64];
  __shared__ __align__(16) float red_s[256];
  __shared__ __align__(16) float node_s[HD];
  __shared__ float mh_s[8], sum_s[8];

  if (f_We)  { for (int o = tid; o < 64 * HD; o += 256) We_s[o] = f2bf(((const float*)Wep)[o]); }
  else       { for (int o = tid; o < 64 * HD; o += 256) We_s[o] = ((const uint16_t*)Wep)[o]; }
  if (f_Weo) { for (int o = tid; o < HD * 64; o += 256) Weo_s[o] = f2bf(((const float*)Weop)[o]); }
  else       { for (int o = tid; o < HD * 64; o += 256) Weo_s[o] = ((const uint16_t*)Weop)[o]; }
  if (tid < HD) {
    q_s[tid] = bf2f(qf[(bb * NN + i) * HD + tid]);
    be_s[tid] = f_be ? ((const float*)bep)[tid] : bf2f(((const uint16_t*)bep)[tid]);
  }
  if (tid < 64)
    beo_s[tid] = f_beo ? ((const float*)beop)[tid] : bf2f(((const uint16_t*)beop)[tid]);
  __syncthreads();

  const size_t row_base = (size_t)(bb * NN + i) * NN * 64;
  const uint16_t* krow = kf + (size_t)bb * NN * HD;
  const uint16_t* vrow = vf + (size_t)bb * NN * HD;
  const float* mrow = mbias + bb * NN;

  for (int jt = 0; jt < NN; jt += TJ) {
    // ---- stage edge_attr tile (TJ x 64 -> bf16 LDS) ----
    if (f_ea) {
      const float* src = (const float*)eap + row_base + (size_t)jt * 64;
      for (int w = tid; w < TJ * 64; w += 256) ea_s[w] = f2bf(src[w]);
    } else {
      const uint32_t* src = (const uint32_t*)((const uint16_t*)eap + row_base + (size_t)jt * 64);
      uint32_t* dst = (uint32_t*)ea_s;
      for (int w = tid; w < TJ * 64 / 2; w += 256) dst[w] = src[w];
    }
    __syncthreads();

    // ---- e = ea @ We + be ; raw = q * k * e ----
    {
      const int cq = tid & 31;       // column quad: c = 4*cq
      const int rb = tid >> 5;       // 0..7
      #pragma unroll 1
      for (int p = 0; p < 2; ++p) {
        const int r0 = p * 16 + rb;
        const int r1 = r0 + 8;
        float4 acc0 = *(const float4*)&be_s[4 * cq];
        float4 acc1 = acc0;
        const ushort4* a0p = (const ushort4*)(ea_s + r0 * 64);
        const ushort4* a1p = (const ushort4*)(ea_s + r1 * 64);
        #pragma unroll
        for (int k4 = 0; k4 < 16; ++k4) {
          ushort4 a0u = a0p[k4], a1u = a1p[k4];
          float a0f[4] = {bf2f(a0u.x), bf2f(a0u.y), bf2f(a0u.z), bf2f(a0u.w)};
          float a1f[4] = {bf2f(a1u.x), bf2f(a1u.y), bf2f(a1u.z), bf2f(a1u.w)};
          #pragma unroll
          for (int q = 0; q < 4; ++q) {
            const int kk = k4 * 4 + q;
            ushort4 wu = *(const ushort4*)&We_s[kk * HD + 4 * cq];
            float w0 = bf2f(wu.x), w1 = bf2f(wu.y), w2 = bf2f(wu.z), w3 = bf2f(wu.w);
            acc0.x = fmaf(a0f[q], w0, acc0.x); acc0.y = fmaf(a0f[q], w1, acc0.y);
            acc0.z = fmaf(a0f[q], w2, acc0.z); acc0.w = fmaf(a0f[q], w3, acc0.w);
            acc1.x = fmaf(a1f[q], w0, acc1.x); acc1.y = fmaf(a1f[q], w1, acc1.y);
            acc1.z = fmaf(a1f[q], w2, acc1.z); acc1.w = fmaf(a1f[q], w3, acc1.w);
          }
        }
        const float4 q4 = *(const float4*)&q_s[4 * cq];
        const ushort4 k0u = *(const ushort4*)&krow[(size_t)(jt + r0) * HD + 4 * cq];
        const ushort4 k1u = *(const ushort4*)&krow[(size_t)(jt + r1) * HD + 4 * cq];
        float4 o0, o1;
        o0.x = q4.x * bf2f(k0u.x) * acc0.x; o0.y = q4.y * bf2f(k0u.y) * acc0.y;
        o0.z = q4.z * bf2f(k0u.z) * acc0.z; o0.w = q4.w * bf2f(k0u.w) * acc0.w;
        o1.x = q4.x * bf2f(k1u.x) * acc1.x; o1.y = q4.y * bf2f(k1u.y) * acc1.y;
        o1.z = q4.z * bf2f(k1u.z) * acc1.z; o1.w = q4.w * bf2f(k1u.w) * acc1.w;
        *(float4*)&raw_s[r0 * HD + 4 * cq] = o0;
        *(float4*)&raw_s[r1 * HD + 4 * cq] = o1;
      }
    }
    __syncthreads();

    // ---- att logits: sum over d of raw, /4, + mask bias ----
    {
      const int r = tid >> 3, h = tid & 7;
      const float* rp = raw_s + r * HD + h * 16;
      float s = 0.f;
      #pragma unroll
      for (int d = 0; d < 16; ++d) s += rp[d];
      att_s[(jt + r) * 8 + h] = f2bf(s * 0.25f + mrow[jt + r]);
    }

    // ---- edge_out tile = raw @ Weo + beo (fp32 stores) ----
    {
      const int cq = tid & 15;       // c = 4*cq in 0..60
      const int rb = tid >> 4;       // 0..15
      const int r0 = rb, r1 = rb + 16;
      float4 acc0 = *(const float4*)&beo_s[4 * cq];
      float4 acc1 = acc0;
      const float4* a0p = (const float4*)(raw_s + r0 * HD);
      const float4* a1p = (const float4*)(raw_s + r1 * HD);
      #pragma unroll 8
      for (int k4 = 0; k4 < 32; ++k4) {
        float4 a0v = a0p[k4], a1v = a1p[k4];
        float a0f[4] = {a0v.x, a0v.y, a0v.z, a0v.w};
        float a1f[4] = {a1v.x, a1v.y, a1v.z, a1v.w};
        #pragma unroll
        for (int q = 0; q < 4; ++q) {
          const int kk = k4 * 4 + q;
          ushort4 wu = *(const ushort4*)&Weo_s[kk * 64 + 4 * cq];
          float w0 = bf2f(wu.x), w1 = bf2f(wu.y), w2 = bf2f(wu.z), w3 = bf2f(wu.w);
          acc0.x = fmaf(a0f[q], w0, acc0.x); acc0.y = fmaf(a0f[q], w1, acc0.y);
          acc0.z = fmaf(a0f[q], w2, acc0.z); acc0.w = fmaf(a0f[q], w3, acc0.w);
          acc1.x = fmaf(a1f[q], w0, acc1.x); acc1.y = fmaf(a1f[q], w1, acc1.y);
          acc1.z = fmaf(a1f[q], w2, acc1.z); acc1.w = fmaf(a1f[q], w3, acc1.w);
        }
      }
      *(float4*)&edge_out[row_base + (size_t)(jt + r0) * 64 + 4 * cq] = acc0;
      *(float4*)&edge_out[row_base + (size_t)(jt + r1) * 64 + 4 * cq] = acc1;
    }
    __syncthreads();
  }

  // ---- softmax over j, per head (bias already in logits; sum >= 1 always) ----
  {
    const int h = tid >> 5;
    const int lane = tid & 31;
    float m = -3.4e38f;
    for (int j = lane; j < NN; j += 32) m = fmaxf(m, bf2f(att_s[j * 8 + h]));
    red_s[tid] = m;
    __syncthreads();
    if (lane == 0) {
      float mm = -3.4e38f;
      #pragma unroll
      for (int t = 0; t < 32; ++t) mm = fmaxf(mm, red_s[(h << 5) + t]);
      mh_s[h] = mm;
    }
    __syncthreads();
    const float mm = mh_s[h];
    float s = 0.f;
    for (int j = lane; j < NN; j += 32) {
      float v = __expf(bf2f(att_s[j * 8 + h]) - mm);
      att_s[j * 8 + h] = f2bf(v);
      s += v;
    }
    red_s[tid] = s;
    __syncthreads();
    if (lane == 0) {
      float ss = 0.f;
      #pragma unroll
      for (int t = 0; t < 32; ++t) ss += red_s[(h << 5) + t];
      sum_s[h] = ss;
    }
    __syncthreads();
    const float inv = 1.0f / sum_s[h];
    for (int j = lane; j < NN; j += 32)
      att_s[j * 8 + h] = f2bf(bf2f(att_s[j * 8 + h]) * inv);
  }
  __syncthreads();

  // ---- node = att @ v ----
  {
    const int c = tid & 127;
    const int half = tid >> 7;
    const int h = c >> 4;
    const int j0 = half * 256;
    float acc = 0.f;
    for (int j = j0; j < j0 + 256; ++j)
      acc = fmaf(bf2f(att_s[j * 8 + h]), bf2f(vrow[(size_t)j * HD + c]), acc);
    red_s[tid] = acc;
    __syncthreads();
    if (tid < HD) node_s[tid] = red_s[tid] + red_s[tid + 128];
    __syncthreads();
  }

  // ---- node_out = node @ Wno + bno (fp32 store) ----
  if (tid < HD) {
    float acc = f_bno ? ((const float*)bnop)[tid] : bf2f(((const uint16_t*)bnop)[tid]);
    if (f_Wno) {
      const float* W = (const float*)Wnop;
      #pragma unroll 4
      for (int kk = 0; kk < HD; ++kk) acc = fmaf(node_s[kk], W[kk * HD + tid], acc);
    } else {
      const uint16_t* W = (const uint16_t*)Wnop;
      #pragma unroll 4
      for (int kk = 0; kk < HD; ++kk) acc = fmaf(node_s[kk], bf2f(W[kk * HD + tid]), acc);
    }
    node_out[(bb * NN + i) * HD + tid] = acc;
  }
}

extern "C" void kernel_launch(void* const* d_in, const int* in_sizes, int n_in,
                              void* d_out, int out_size, void* d_ws, size_t ws_size,
                              hipStream_t stream) {
  const int b = in_sizes[0] / (NN * HD);   // = 2
  const int rows = b * NN;                 // = 1024

  int*   flags = (int*)d_ws;                                        // 16 ints
  float* mbias = (float*)((char*)d_ws + 64);                        // rows floats
  uint16_t* qf = (uint16_t*)((char*)d_ws + 64 + 4096);
  uint16_t* kf = qf + (size_t)rows * HD;
  uint16_t* vf = kf + (size_t)rows * HD;

  float* node_out = (float*)d_out;
  float* edge_out = node_out + (size_t)rows * HD;

  DetectArgs da;
  const int float_idx[10] = {0, 1, 3, 4, 5, 6, 7, 8, 9, 10};
  for (int t = 0; t < 10; ++t) {
    da.p[t] = (const uint16_t*)d_in[float_idx[t]];
    da.n[t] = in_sizes[float_idx[t]];
  }

  detect_kernel<<<1, 64, 0, stream>>>(da, flags);
  mask_bias_kernel<<<(rows + 255) / 256, 256, 0, stream>>>((const uint32_t*)d_in[2], mbias, rows);
  qkv_kernel<<<rows, 128, 0, stream>>>(d_in[0], d_in[3], d_in[4], flags, qf, kf, vf);
  gat_main_kernel<<<rows, 256, 0, stream>>>(d_in[1], d_in[5], d_in[6], d_in[7], d_in[8],
                                            d_in[9], d_in[10], flags,
                                            qf, kf, vf, mbias, node_out, edge_out);
}

// Round 6
// 523.299 us; speedup vs baseline: 2.2951x; 2.2951x over previous
//
#include <hip/hip_runtime.h>
#include <hip/hip_bf16.h>
#include <stdint.h>

#define NN 512
#define HD 128

typedef __attribute__((ext_vector_type(8))) short bf16x8;
typedef __attribute__((ext_vector_type(4))) float f32x4;

static __device__ __forceinline__ float bf2f(unsigned short u) {
  union { uint32_t u32; float f; } cv; cv.u32 = ((uint32_t)u) << 16; return cv.f;
}
static __device__ __forceinline__ unsigned short f2bf(float f) {
  union { float f; uint32_t u; } cv; cv.f = f;
  return (unsigned short)((cv.u + 0x7FFFu + ((cv.u >> 16) & 1u)) >> 16);
}

struct DetectArgs { const uint16_t* p[10]; int n[10]; };

// Per-tensor dtype sniffing (flags[ti]=1 -> fp32, 0 -> bf16). One block per
// tensor so the latency-bound scans run in parallel (R4: serial version cost
// ~120us). bf16 data passes ~100% of the exponent-window test; fp32-as-u16
// passes ~58%. Threshold 90%.
__global__ __launch_bounds__(256) void detect_kernel(DetectArgs a, int* __restrict__ flags) {
  __shared__ int acc[256];
  const int ti = blockIdx.x;
  int n = a.n[ti]; if (n > 2048) n = 2048;
  int g = 0;
  for (int w = threadIdx.x; w < n; w += 256) {
    uint16_t v = a.p[ti][w];
    int e = (v >> 7) & 0xFF;
    g += (v == 0u || (e >= 90 && e <= 133)) ? 1 : 0;
  }
  acc[threadIdx.x] = g;
  __syncthreads();
  for (int s = 128; s > 0; s >>= 1) {
    if (threadIdx.x < s) acc[threadIdx.x] += acc[threadIdx.x + s];
    __syncthreads();
  }
  if (threadIdx.x == 0) flags[ti] = (acc[0] * 10 < n * 9) ? 1 : 0;
}

__global__ __launch_bounds__(256) void mask_bias_kernel(const uint32_t* __restrict__ raw,
                                                        float* __restrict__ mbias, int count) {
  int inspect = count >> 2; if (inspect > 256) inspect = 256;
  bool ok_i32 = true, ok_f32 = true, ok_bf16 = true;
  #pragma unroll 1
  for (int w = 0; w < inspect; ++w) {
    uint32_t v = raw[w];
    if (v > 1u) ok_i32 = false;
    if (!(v == 0u || v == 0x3F800000u)) ok_f32 = false;
    uint32_t lo = v & 0xFFFFu, hi = v >> 16;
    if (!((lo == 0u || lo == 0x3F80u) && (hi == 0u || hi == 0x3F80u))) ok_bf16 = false;
  }
  int idx = blockIdx.x * 256 + threadIdx.x;
  if (idx < count) {
    bool on;
    if (ok_i32 || ok_f32) on = raw[idx] != 0u;
    else if (ok_bf16)     on = ((const uint16_t*)raw)[idx] != 0u;
    else                  on = ((const uint8_t*)raw)[idx] != 0u;
    mbias[idx] = on ? 0.0f : -1e30f;
  }
}

// qkv = x @ Wqkv + bqkv ; q,k,v stored bf16 in workspace.
__global__ __launch_bounds__(128) void qkv_kernel(const void* __restrict__ xp,
                                                  const void* __restrict__ Wp,
                                                  const void* __restrict__ bp,
                                                  const int* __restrict__ flags,
                                                  uint16_t* __restrict__ qf,
                                                  uint16_t* __restrict__ kf,
                                                  uint16_t* __restrict__ vf) {
  const int f_x = flags[0], f_W = flags[2], f_b = flags[3];
  const int row = blockIdx.x;
  const int t = threadIdx.x;
  __shared__ float xs[HD];
  xs[t] = f_x ? ((const float*)xp)[row * HD + t] : bf2f(((const uint16_t*)xp)[row * HD + t]);
  __syncthreads();
  float aq = 0.f, ak = 0.f, av = 0.f;
  if (f_W) {
    const float* W = (const float*)Wp;
    #pragma unroll 4
    for (int kk = 0; kk < HD; ++kk) {
      float xv = xs[kk]; const float* wr = W + kk * 384;
      aq = fmaf(xv, wr[t], aq);
      ak = fmaf(xv, wr[128 + t], ak);
      av = fmaf(xv, wr[256 + t], av);
    }
  } else {
    const uint16_t* W = (const uint16_t*)Wp;
    #pragma unroll 4
    for (int kk = 0; kk < HD; ++kk) {
      float xv = xs[kk]; const uint16_t* wr = W + kk * 384;
      aq = fmaf(xv, bf2f(wr[t]), aq);
      ak = fmaf(xv, bf2f(wr[128 + t]), ak);
      av = fmaf(xv, bf2f(wr[256 + t]), av);
    }
  }
  float bq = f_b ? ((const float*)bp)[t]       : bf2f(((const uint16_t*)bp)[t]);
  float bk = f_b ? ((const float*)bp)[128 + t] : bf2f(((const uint16_t*)bp)[128 + t]);
  float bv = f_b ? ((const float*)bp)[256 + t] : bf2f(((const uint16_t*)bp)[256 + t]);
  qf[row * HD + t] = f2bf(aq + bq);
  kf[row * HD + t] = f2bf(ak + bk);
  vf[row * HD + t] = f2bf(av + bv);
}

// One block per (b,i); 4 waves; MFMA 16x16x32 bf16 for both inner GEMMs.
// q folded into We/be (raw = k .* (ea@(We*q) + be*q)). Barrier-free j-loop:
// each wave owns disjoint 16-row j-bands end-to-end.
__global__ __launch_bounds__(256) void gat_main_kernel(
    const void* __restrict__ eap,
    const void* __restrict__ Wep,  const void* __restrict__ bep,
    const void* __restrict__ Wnop, const void* __restrict__ bnop,
    const void* __restrict__ Weop, const void* __restrict__ beop,
    const int* __restrict__ flags,
    const uint16_t* __restrict__ qf, const uint16_t* __restrict__ kf,
    const uint16_t* __restrict__ vf, const float* __restrict__ mbias,
    float* __restrict__ node_out, float* __restrict__ edge_out) {
  const int tid = threadIdx.x;
  const int w = tid >> 6, lane = tid & 63;
  const int l15 = lane & 15, quad = lane >> 4;
  const int bb = blockIdx.x >> 9;
  const int i  = blockIdx.x & (NN - 1);
  const int f_ea = flags[1], f_We = flags[4], f_be = flags[5];
  const int f_Wno = flags[6], f_bno = flags[7], f_Weo = flags[8], f_beo = flags[9];

  // Frag-ready weight layouts: [tile][kstep][lane][8] (ds_read_b128/lane).
  __shared__ __align__(16) uint16_t B1f[8 * 2 * 64 * 8];   // We*q  16 KB
  __shared__ __align__(16) uint16_t B2f[4 * 4 * 64 * 8];   // Weo   16 KB
  __shared__ __align__(16) uint16_t raw_s[4 * 16 * 136];   // per-wave, pad 8 -> 17 KB
  __shared__ __align__(16) uint16_t att_s[NN * 8];         // 8 KB
  __shared__ __align__(16) float q_s[HD];
  __shared__ __align__(16) float beq_s[HD];
  __shared__ __align__(16) float beo_s[64];
  __shared__ __align__(16) float red_s[256];
  __shared__ __align__(16) float node_s[HD];
  __shared__ float mh_s[8], sum_s[8];

  if (tid < HD) q_s[tid] = bf2f(qf[(bb * NN + i) * HD + tid]);
  if (tid >= 128 && tid < 192) {
    int c = tid - 128;
    beo_s[c] = f_beo ? ((const float*)beop)[c] : bf2f(((const uint16_t*)beop)[c]);
  }
  __syncthreads();

  if (tid < HD) {
    float b = f_be ? ((const float*)bep)[tid] : bf2f(((const uint16_t*)bep)[tid]);
    beq_s[tid] = b * q_s[tid];
  }
  // Build B1 frags: element = We[k][c] * q[c]; slot = t*128 + s*64 + ln.
  for (int slot = tid; slot < 1024; slot += 256) {
    const int t = slot >> 7, s = (slot >> 6) & 1, ln = slot & 63;
    const int c = t * 16 + (ln & 15);
    const int k0 = s * 32 + (ln >> 4) * 8;
    const float qc = q_s[c];
    bf16x8 fr;
    if (f_We) {
      const float* W = (const float*)Wep;
      #pragma unroll
      for (int e = 0; e < 8; ++e) fr[e] = (short)f2bf(W[(k0 + e) * HD + c] * qc);
    } else {
      const uint16_t* W = (const uint16_t*)Wep;
      #pragma unroll
      for (int e = 0; e < 8; ++e) fr[e] = (short)f2bf(bf2f(W[(k0 + e) * HD + c]) * qc);
    }
    *(bf16x8*)&B1f[slot * 8] = fr;
  }
  // Build B2 frags: element = Weo[k][c]; slot = t2*256 + s*64 + ln (1024 slots!
  // R5 bug: bound was 512 -> tiles t2=2,3 read uninitialized LDS -> NaN).
  for (int slot = tid; slot < 1024; slot += 256) {
    const int t2 = slot >> 8, s = (slot >> 6) & 3, ln = slot & 63;
    const int c = t2 * 16 + (ln & 15);
    const int k0 = s * 32 + (ln >> 4) * 8;
    bf16x8 fr;
    if (f_Weo) {
      const float* W = (const float*)Weop;
      #pragma unroll
      for (int e = 0; e < 8; ++e) fr[e] = (short)f2bf(W[(k0 + e) * 64 + c]);
    } else {
      const uint16_t* W = (const uint16_t*)Weop;
      #pragma unroll
      for (int e = 0; e < 8; ++e) fr[e] = (short)W[(k0 + e) * 64 + c];
    }
    *(bf16x8*)&B2f[slot * 8] = fr;
  }
  __syncthreads();

  const size_t io_base = (size_t)(bb * NN + i) * NN * 64;   // elements
  const uint16_t* kbase = kf + (size_t)bb * NN * HD;
  const uint16_t* vrow  = vf + (size_t)bb * NN * HD;
  const float* mrow = mbias + bb * NN;
  uint16_t* rws = raw_s + w * 16 * 136;

  for (int band = w; band < 32; band += 4) {
    const int j0 = band * 16;
    // ---- A1 fragments straight from global edge_attr (cvt fp32->bf16) ----
    bf16x8 A1[2];
    if (f_ea) {
      const float* ea = (const float*)eap + io_base + (size_t)(j0 + l15) * 64 + quad * 8;
      #pragma unroll
      for (int s = 0; s < 2; ++s) {
        float4 u0 = *(const float4*)(ea + s * 32);
        float4 u1 = *(const float4*)(ea + s * 32 + 4);
        bf16x8 a;
        a[0] = (short)f2bf(u0.x); a[1] = (short)f2bf(u0.y);
        a[2] = (short)f2bf(u0.z); a[3] = (short)f2bf(u0.w);
        a[4] = (short)f2bf(u1.x); a[5] = (short)f2bf(u1.y);
        a[6] = (short)f2bf(u1.z); a[7] = (short)f2bf(u1.w);
        A1[s] = a;
      }
    } else {
      const uint16_t* ea = (const uint16_t*)eap + io_base + (size_t)(j0 + l15) * 64 + quad * 8;
      A1[0] = *(const bf16x8*)(ea);
      A1[1] = *(const bf16x8*)(ea + 32);
    }

    // ---- GEMM1: e_q = ea @ (We*q) + be*q ----
    f32x4 acc[8];
    #pragma unroll
    for (int t = 0; t < 8; ++t) {
      const float bv = beq_s[t * 16 + l15];
      f32x4 a = {bv, bv, bv, bv};
      a = __builtin_amdgcn_mfma_f32_16x16x32_bf16(
            A1[0], *(const bf16x8*)&B1f[(t * 2 + 0) * 512 + lane * 8], a, 0, 0, 0);
      a = __builtin_amdgcn_mfma_f32_16x16x32_bf16(
            A1[1], *(const bf16x8*)&B1f[(t * 2 + 1) * 512 + lane * 8], a, 0, 0, 0);
      acc[t] = a;
    }

    // ---- raw = k .* e_q ; store bf16 to per-wave LDS (C-layout) ----
    #pragma unroll
    for (int t = 0; t < 8; ++t) {
      const int c = t * 16 + l15;
      #pragma unroll
      for (int r = 0; r < 4; ++r) {
        const int jr = quad * 4 + r;
        const float kv = bf2f(kbase[(size_t)(j0 + jr) * HD + c]);
        rws[jr * 136 + c] = f2bf(acc[t][r] * kv);
      }
    }

    // ---- logits: per-head row sums of raw (+ mask bias) ----
    #pragma unroll
    for (int u = 0; u < 2; ++u) {
      const int id = lane * 2 + u;
      const int jr = id >> 3, h = id & 7;
      float s = 0.f;
      #pragma unroll
      for (int d = 0; d < 16; ++d) s += bf2f(rws[jr * 136 + h * 16 + d]);
      att_s[(j0 + jr) * 8 + h] = f2bf(s * 0.25f + mrow[j0 + jr]);
    }

    // ---- GEMM2: edge_out = raw @ Weo + beo (A-frags from LDS round-trip) ----
    bf16x8 A2[4];
    #pragma unroll
    for (int s = 0; s < 4; ++s)
      A2[s] = *(const bf16x8*)&rws[l15 * 136 + s * 32 + quad * 8];
    #pragma unroll
    for (int t2 = 0; t2 < 4; ++t2) {
      const float bv = beo_s[t2 * 16 + l15];
      f32x4 a2 = {bv, bv, bv, bv};
      #pragma unroll
      for (int s = 0; s < 4; ++s)
        a2 = __builtin_amdgcn_mfma_f32_16x16x32_bf16(
               A2[s], *(const bf16x8*)&B2f[(t2 * 4 + s) * 512 + lane * 8], a2, 0, 0, 0);
      #pragma unroll
      for (int r = 0; r < 4; ++r)
        edge_out[io_base + (size_t)(j0 + quad * 4 + r) * 64 + t2 * 16 + l15] = a2[r];
    }
  }
  __syncthreads();

  // ---- softmax over j, per head (bias already in logits; sum >= 1 always) ----
  {
    const int h = tid >> 5;
    const int l32 = tid & 31;
    float m = -3.4e38f;
    for (int j = l32; j < NN; j += 32) m = fmaxf(m, bf2f(att_s[j * 8 + h]));
    red_s[tid] = m;
    __syncthreads();
    if (l32 == 0) {
      float mm = -3.4e38f;
      #pragma unroll
      for (int t = 0; t < 32; ++t) mm = fmaxf(mm, red_s[(h << 5) + t]);
      mh_s[h] = mm;
    }
    __syncthreads();
    const float mm = mh_s[h];
    float s = 0.f;
    for (int j = l32; j < NN; j += 32) {
      float v = __expf(bf2f(att_s[j * 8 + h]) - mm);
      att_s[j * 8 + h] = f2bf(v);
      s += v;
    }
    red_s[tid] = s;
    __syncthreads();
    if (l32 == 0) {
      float ss = 0.f;
      #pragma unroll
      for (int t = 0; t < 32; ++t) ss += red_s[(h << 5) + t];
      sum_s[h] = ss;
    }
    __syncthreads();
    const float inv = 1.0f / sum_s[h];
    for (int j = l32; j < NN; j += 32)
      att_s[j * 8 + h] = f2bf(bf2f(att_s[j * 8 + h]) * inv);
  }
  __syncthreads();

  // ---- node = att @ v ----
  {
    const int c = tid & 127;
    const int half = tid >> 7;
    const int h = c >> 4;
    const int j0 = half * 256;
    float acc = 0.f;
    for (int j = j0; j < j0 + 256; ++j)
      acc = fmaf(bf2f(att_s[j * 8 + h]), bf2f(vrow[(size_t)j * HD + c]), acc);
    red_s[tid] = acc;
    __syncthreads();
    if (tid < HD) node_s[tid] = red_s[tid] + red_s[tid + 128];
    __syncthreads();
  }

  // ---- node_out = node @ Wno + bno ----
  if (tid < HD) {
    float acc = f_bno ? ((const float*)bnop)[tid] : bf2f(((const uint16_t*)bnop)[tid]);
    if (f_Wno) {
      const float* W = (const float*)Wnop;
      #pragma unroll 4
      for (int kk = 0; kk < HD; ++kk) acc = fmaf(node_s[kk], W[kk * HD + tid], acc);
    } else {
      const uint16_t* W = (const uint16_t*)Wnop;
      #pragma unroll 4
      for (int kk = 0; kk < HD; ++kk) acc = fmaf(node_s[kk], bf2f(W[kk * HD + tid]), acc);
    }
    node_out[(bb * NN + i) * HD + tid] = acc;
  }
}

extern "C" void kernel_launch(void* const* d_in, const int* in_sizes, int n_in,
                              void* d_out, int out_size, void* d_ws, size_t ws_size,
                              hipStream_t stream) {
  const int b = in_sizes[0] / (NN * HD);   // = 2
  const int rows = b * NN;                 // = 1024

  int*   flags = (int*)d_ws;                                        // 16 ints
  float* mbias = (float*)((char*)d_ws + 64);                        // rows floats
  uint16_t* qf = (uint16_t*)((char*)d_ws + 64 + 4096);
  uint16_t* kf = qf + (size_t)rows * HD;
  uint16_t* vf = kf + (size_t)rows * HD;

  float* node_out = (float*)d_out;
  float* edge_out = node_out + (size_t)rows * HD;

  DetectArgs da;
  const int float_idx[10] = {0, 1, 3, 4, 5, 6, 7, 8, 9, 10};
  for (int t = 0; t < 10; ++t) {
    da.p[t] = (const uint16_t*)d_in[float_idx[t]];
    da.n[t] = in_sizes[float_idx[t]];
  }

  detect_kernel<<<10, 256, 0, stream>>>(da, flags);
  mask_bias_kernel<<<(rows + 255) / 256, 256, 0, stream>>>((const uint32_t*)d_in[2], mbias, rows);
  qkv_kernel<<<rows, 128, 0, stream>>>(d_in[0], d_in[3], d_in[4], flags, qf, kf, vf);
  gat_main_kernel<<<rows, 256, 0, stream>>>(d_in[1], d_in[5], d_in[6], d_in[7], d_in[8],
                                            d_in[9], d_in[10], flags,
                                            qf, kf, vf, mbias, node_out, edge_out);
}